// Round 17
// baseline (180.835 us; speedup 1.0000x reference)
//
#include <hip/hip_runtime.h>
#include <hip/hip_bf16.h>

// Problem constants
#define NB    2048   // batch
#define SS    200    // seq len
#define NTIL  13     // s-tiles of 16 (208 padded)
#define DSEQ  256
#define DITEM 64
#define AA    128    // attn dim (H=1, HD=128)

typedef __bf16 bf16x8 __attribute__((ext_vector_type(8)));
typedef float  f32x4  __attribute__((ext_vector_type(4)));

__device__ __forceinline__ float prelu_f(float x, float a) { return x >= 0.f ? x : a * x; }

// 16-lane reduce via DPP row_ror — VALU pipe only; result valid in all 16 lanes.
#define ROR_F(x, n) __int_as_float(__builtin_amdgcn_update_dpp(0, __float_as_int(x), 0x120 + (n), 0xf, 0xf, true))
__device__ __forceinline__ float row_sum16(float x) {
    x += ROR_F(x, 1); x += ROR_F(x, 2); x += ROR_F(x, 4); x += ROR_F(x, 8);
    return x;
}
__device__ __forceinline__ float row_max16(float x) {
    x = fmaxf(x, ROR_F(x, 1)); x = fmaxf(x, ROR_F(x, 2));
    x = fmaxf(x, ROR_F(x, 4)); x = fmaxf(x, ROR_F(x, 8));
    return x;
}

// ---------------- prep: W_k|W_v -> bf16 [256 rows][512B], XOR-swizzled within rows
__global__ void prep_kernel(const float* __restrict__ Wk, const float* __restrict__ Wv,
                            __hip_bfloat16* __restrict__ Wb) {
    int idx = blockIdx.x * 256 + threadIdx.x;   // 256 blocks -> 65536
    int a = idx >> 8, d = idx & 255;
    float v = (a < 128) ? Wk[a * 256 + d] : Wv[(a - 128) * 256 + d];
    int boff = (d * 2) ^ ((a & 7) << 4);
    Wb[a * 256 + (boff >> 1)] = __float2bfloat16(v);
}

// per-thread staging, stream s: thread covers row srow, 64B f32 chunk -> 32B bf16
#define ISSUE(tt, s)                                                            \
    {                                                                           \
        int r_ = (tt) * 16 + srow; r_ = r_ < SS ? r_ : SS - 1;                  \
        const float* xp_ = Xp##s + (size_t)r_ * DSEQ + chunk * 16;              \
        st0 = *reinterpret_cast<const f32x4*>(xp_);                             \
        st1 = *reinterpret_cast<const f32x4*>(xp_ + 4);                         \
        st2 = *reinterpret_cast<const f32x4*>(xp_ + 8);                         \
        st3 = *reinterpret_cast<const f32x4*>(xp_ + 12);                        \
    }

#define STAGE(tt, s)                                                            \
    {                                                                           \
        bf16x8 va_, vb_;                                                        \
        va_[0]=(__bf16)st0[0]; va_[1]=(__bf16)st0[1]; va_[2]=(__bf16)st0[2]; va_[3]=(__bf16)st0[3]; \
        va_[4]=(__bf16)st1[0]; va_[5]=(__bf16)st1[1]; va_[6]=(__bf16)st1[2]; va_[7]=(__bf16)st1[3]; \
        vb_[0]=(__bf16)st2[0]; vb_[1]=(__bf16)st2[1]; vb_[2]=(__bf16)st2[2]; vb_[3]=(__bf16)st2[3]; \
        vb_[4]=(__bf16)st3[0]; vb_[5]=(__bf16)st3[1]; vb_[6]=(__bf16)st3[2]; vb_[7]=(__bf16)st3[3]; \
        *reinterpret_cast<bf16x8*>(xb##s + ((tt) & 1) * 8192 + wrA) = va_;      \
        *reinterpret_cast<bf16x8*>(xb##s + ((tt) & 1) * 8192 + wrB) = vb_;      \
    }

// deferred online-softmax + V-fold of tile `tp`, stream s (2 col-groups)
#define SMFOLD(tp, s)                                                           \
    {                                                                           \
        const int q_ = (tp) & 1;                                                \
        const int s0_ = (tp) * 16;                                              \
        f32x4 r_ = *reinterpret_cast<const f32x4*>(&sp##s[q_][c][0]);           \
        float sc_ = (r_[0] + r_[1] + r_[2] + r_[3]) * inv_scale;                \
        sc_ = mask##s[s0_ + c] ? -1e9f : sc_;                                   \
        if (tid < 16) score_buf##s[s0_ + tid] = sc_;                            \
        float tmax_ = row_max16(sc_);                                           \
        float nm_ = fmaxf(m##s, tmax_);                                         \
        float fs_ = __expf(m##s - nm_);                                         \
        float e_  = __expf(sc_ - nm_);                                          \
        float ls_ = row_sum16(e_);                                              \
        l##s = l##s * fs_ + ls_; m##s = nm_;                                    \
        oaccA##s *= fs_; oaccB##s *= fs_;                                       \
        _Pragma("unroll")                                                       \
        for (int i_ = 0; i_ < 4; i_++) {                                        \
            float ew_ = __shfl(e_, (lane & 48) | (rg * 4 + i_), 64);            \
            oaccA##s += ew_ * prelu_f(aVpA##s[i_], pa);                         \
            oaccB##s += ew_ * prelu_f(aVpB##s[i_], pa);                         \
        }                                                                       \
    }

// compute tile tt, stream s: 2 col-groups x {K,V} = 4 chains; weights from L2
#define COMPUTE(tt, s)                                                          \
    {                                                                           \
        const char* rb_ = xb##s + ((tt) & 1) * 8192 + c * 512;                  \
        f32x4 aK0 = {0.f,0.f,0.f,0.f}, aV0 = {0.f,0.f,0.f,0.f};                 \
        f32x4 aK1 = {0.f,0.f,0.f,0.f}, aV1 = {0.f,0.f,0.f,0.f};                 \
        _Pragma("unroll")                                                       \
        for (int k = 0; k < 8; k++) {                                           \
            const int o = (k * 64 + rg * 16) ^ rswz;                            \
            bf16x8 af  = *reinterpret_cast<const bf16x8*>(rb_ + o);             \
            bf16x8 bk0 = *reinterpret_cast<const bf16x8*>(kb0 + o);             \
            bf16x8 bv0 = *reinterpret_cast<const bf16x8*>(vb0 + o);             \
            bf16x8 bk1 = *reinterpret_cast<const bf16x8*>(kb1 + o);             \
            bf16x8 bv1 = *reinterpret_cast<const bf16x8*>(vb1 + o);             \
            aK0 = __builtin_amdgcn_mfma_f32_16x16x32_bf16(af, bk0, aK0, 0, 0, 0); \
            aK1 = __builtin_amdgcn_mfma_f32_16x16x32_bf16(af, bk1, aK1, 0, 0, 0); \
            aV0 = __builtin_amdgcn_mfma_f32_16x16x32_bf16(af, bv0, aV0, 0, 0, 0); \
            aV1 = __builtin_amdgcn_mfma_f32_16x16x32_bf16(af, bv1, aV1, 0, 0, 0); \
        }                                                                       \
        float pr_[4];                                                           \
        _Pragma("unroll")                                                       \
        for (int i = 0; i < 4; i++)                                             \
            pr_[i] = row_sum16(prelu_f(aK0[i], pa) * uw0##s + prelu_f(aK1[i], pa) * uw1##s); \
        if (c == 0) {                                                           \
            _Pragma("unroll")                                                   \
            for (int i = 0; i < 4; i++) sp##s[(tt) & 1][rg * 4 + i][w] = pr_[i]; \
        }                                                                       \
        aVpA##s = aV0; aVpB##s = aV1;                                           \
    }

// ---------------- main: 256-thread block (4 waves) per TWO batch rows.
// Wave w owns cols [32w,32w+32); all weights streamed from L2; ~40 KB LDS,
// ~115 live VGPRs -> 4 blocks/CU x 2 streams = 8 independent contexts/CU.
__global__ __launch_bounds__(256)
void pool_main(
    const float* __restrict__ X,      // [2048,200,256]
    const int*   __restrict__ maskp,  // [2048,200] 1 = pad
    const float* __restrict__ temb,   // [2048,64]
    const float* __restrict__ Wq,     // [128,64]
    const float* __restrict__ Wker,   // [128,128]
    const float* __restrict__ ffnW,   // [256,128]
    const float* __restrict__ ffnb,   // [256]
    const float* __restrict__ prelu_a,
    const __hip_bfloat16* __restrict__ Wb,  // ws: swizzled bf16 weights [256][256]
    float* __restrict__ out)          // [2048*256] ffn, then [2048*200] attn
{
    __shared__ __hip_bfloat16 Xt0[2][16][256];   // 8 KB x2
    __shared__ __hip_bfloat16 Xt1[2][16][256];
    __shared__ float sp0[2][16][4], sp1[2][16][4];
    __shared__ float score_buf0[208], score_buf1[208];
    __shared__ float out_vec0[AA], out_vec1[AA];
    __shared__ float tq0[DITEM], tq1[DITEM];
    __shared__ float Qv0[AA], Qv1[AA];
    __shared__ float uv0[AA], uv1[AA];
    __shared__ int   mask0[208], mask1[208];

    const int tid  = threadIdx.x;     // 0..255
    const int w    = tid >> 6;        // wave 0..3
    const int lane = tid & 63;
    const int c    = lane & 15;
    const int rg   = lane >> 4;
    const int b0   = blockIdx.x * 2;
    const int b1   = b0 + 1;
    const float pa = *prelu_a;
    const float inv_scale = 0.08838834764831845f;  // 1/sqrt(128)

    const int srow  = tid >> 4;       // staging row 0..15
    const int chunk = tid & 15;       // 64B f32 chunk in row
    const int wswz  = (srow & 7) << 4;
    const int wrA   = srow * 512 + ((chunk * 32) ^ wswz);
    const int wrB   = srow * 512 + ((chunk * 32 + 16) ^ wswz);
    char* xb0 = (char*)&Xt0[0][0][0];
    char* xb1 = (char*)&Xt1[0][0][0];
    const int rswz = (c & 7) << 4;
    const float* Xp0 = X + (size_t)b0 * SS * DSEQ;
    const float* Xp1 = X + (size_t)b1 * SS * DSEQ;

    // weight fragment base pointers (L2-resident, shared chip-wide)
    const char* kb0 = (const char*)Wb + (size_t)(32 * w + c) * 512;
    const char* kb1 = kb0 + 8192;
    const char* vb0 = kb0 + 65536;
    const char* vb1 = kb1 + 65536;

    // ---- small staging + tile-0 issue
    if (tid < DITEM)                  tq0[tid]      = temb[(size_t)b0 * DITEM + tid];
    else if (tid < 2 * DITEM)         tq1[tid - 64] = temb[(size_t)b1 * DITEM + tid - 64];
    if (tid < 208) {
        mask0[tid] = (tid < SS) ? maskp[(size_t)b0 * SS + tid] : 1;
        mask1[tid] = (tid < SS) ? maskp[(size_t)b1 * SS + tid] : 1;
    }
    f32x4 st0, st1, st2, st3;
    ISSUE(0, 0);
    __syncthreads();

    // ---- Q both streams (tid<128 -> b0, else b1)
    {
        const int o = tid & 127;
        const float* tqp = (tid < 128) ? tq0 : tq1;
        float acc = 0.f;
        #pragma unroll
        for (int d4 = 0; d4 < 16; d4++) {
            f32x4 tv = *reinterpret_cast<const f32x4*>(&tqp[d4 * 4]);
            f32x4 wq4 = *reinterpret_cast<const f32x4*>(Wq + (size_t)o * DITEM + d4 * 4);
            acc += wq4[0]*tv[0] + wq4[1]*tv[1] + wq4[2]*tv[2] + wq4[3]*tv[3];
        }
        if (tid < 128) Qv0[o] = prelu_f(acc, pa); else Qv1[o] = prelu_f(acc, pa);
    }
    __syncthreads();

    // ---- u both streams
    {
        const int o = tid & 127;
        const float* qp = (tid < 128) ? Qv0 : Qv1;
        float acc = 0.f;
        #pragma unroll
        for (int d4 = 0; d4 < 32; d4++) {
            f32x4 qv = *reinterpret_cast<const f32x4*>(&qp[d4 * 4]);
            f32x4 wv4 = *reinterpret_cast<const f32x4*>(Wker + (size_t)o * AA + d4 * 4);
            acc += wv4[0]*qv[0] + wv4[1]*qv[1] + wv4[2]*qv[2] + wv4[3]*qv[3];
        }
        if (tid < 128) uv0[o] = acc; else uv1[o] = acc;
    }
    __syncthreads();
    const float uw00 = uv0[32 * w + c],      uw10 = uv0[32 * w + 16 + c];
    const float uw01 = uv1[32 * w + c],      uw11 = uv1[32 * w + 16 + c];

    // ---- prologue: stage tile 0 both streams
    STAGE(0, 0);
    ISSUE(0, 1);
    STAGE(0, 1);
    __syncthreads();

    // ---- main loop: 1 barrier/tile; staging split around the two COMPUTEs
    float m0 = -INFINITY, l0 = 0.f, oaccA0 = 0.f, oaccB0 = 0.f;
    float m1 = -INFINITY, l1 = 0.f, oaccA1 = 0.f, oaccB1 = 0.f;
    f32x4 aVpA0 = {0.f,0.f,0.f,0.f}, aVpB0 = {0.f,0.f,0.f,0.f};
    f32x4 aVpA1 = {0.f,0.f,0.f,0.f}, aVpB1 = {0.f,0.f,0.f,0.f};

    for (int t = 0; t < NTIL; t++) {
        if (t + 1 < NTIL) ISSUE(t + 1, 0);

        if (t > 0) { SMFOLD(t - 1, 0); SMFOLD(t - 1, 1); }

        COMPUTE(t, 0);

        if (t + 1 < NTIL) { STAGE(t + 1, 0); ISSUE(t + 1, 1); }

        COMPUTE(t, 1);

        if (t + 1 < NTIL) STAGE(t + 1, 1);
        __syncthreads();
    }

    // ---- epilogue: fold last tile, reduce, outputs
    SMFOLD(NTIL - 1, 0); SMFOLD(NTIL - 1, 1);
    oaccA0 += __shfl_xor(oaccA0, 16, 64); oaccA0 += __shfl_xor(oaccA0, 32, 64);
    oaccB0 += __shfl_xor(oaccB0, 16, 64); oaccB0 += __shfl_xor(oaccB0, 32, 64);
    oaccA1 += __shfl_xor(oaccA1, 16, 64); oaccA1 += __shfl_xor(oaccA1, 32, 64);
    oaccB1 += __shfl_xor(oaccB1, 16, 64); oaccB1 += __shfl_xor(oaccB1, 32, 64);
    const float invl0 = 1.0f / l0, invl1 = 1.0f / l1;
    if (lane < 16) {
        out_vec0[32 * w + lane]      = oaccA0 * invl0;
        out_vec0[32 * w + 16 + lane] = oaccB0 * invl0;
        out_vec1[32 * w + lane]      = oaccA1 * invl1;
        out_vec1[32 * w + 16 + lane] = oaccB1 * invl1;
    }
    __syncthreads();

    // attn outputs (both streams; all uniform m/l)
    if (tid < SS) {
        out[(size_t)NB * DSEQ + (size_t)b0 * SS + tid] = __expf(score_buf0[tid] - m0) * invl0;
        out[(size_t)NB * DSEQ + (size_t)b1 * SS + tid] = __expf(score_buf1[tid] - m1) * invl1;
    }

    // FFN: 256 threads, both streams; ffnW row loaded once, used twice
    {
        float acc0 = ffnb[tid], acc1 = acc0;
        #pragma unroll 8
        for (int a4 = 0; a4 < 32; a4++) {
            f32x4 wv4 = *reinterpret_cast<const f32x4*>(ffnW + (size_t)tid * AA + a4 * 4);
            f32x4 ov0 = *reinterpret_cast<const f32x4*>(&out_vec0[a4 * 4]);
            f32x4 ov1 = *reinterpret_cast<const f32x4*>(&out_vec1[a4 * 4]);
            acc0 += wv4[0]*ov0[0] + wv4[1]*ov0[1] + wv4[2]*ov0[2] + wv4[3]*ov0[3];
            acc1 += wv4[0]*ov1[0] + wv4[1]*ov1[1] + wv4[2]*ov1[2] + wv4[3]*ov1[3];
        }
        out[(size_t)b0 * DSEQ + tid] = prelu_f(acc0, pa);
        out[(size_t)b1 * DSEQ + tid] = prelu_f(acc1, pa);
    }
}

extern "C" void kernel_launch(void* const* d_in, const int* in_sizes, int n_in,
                              void* d_out, int out_size, void* d_ws, size_t ws_size,
                              hipStream_t stream) {
    const float* X    = (const float*)d_in[0];
    const int*   mask = (const int*)  d_in[1];
    const float* temb = (const float*)d_in[2];
    const float* Wq   = (const float*)d_in[3];
    const float* Wk   = (const float*)d_in[4];
    const float* Wv   = (const float*)d_in[5];
    const float* Wker = (const float*)d_in[6];
    const float* ffnW = (const float*)d_in[7];
    const float* ffnb = (const float*)d_in[8];
    const float* pa   = (const float*)d_in[9];
    float* out = (float*)d_out;

    __hip_bfloat16* Wb = (__hip_bfloat16*)d_ws;

    prep_kernel<<<256, 256, 0, stream>>>(Wk, Wv, Wb);
    pool_main<<<NB / 2, 256, 0, stream>>>(X, mask, temb, Wq, Wker, ffnW, ffnb, pa, Wb, out);
}